// Round 1
// baseline (292.023 us; speedup 1.0000x reference)
//
#include <hip/hip_runtime.h>
#include <hip/hip_cooperative_groups.h>

namespace cg = cooperative_groups;

// Problem constants (reference: B,H,I,E = 16,16,512,512)
#define B_ 16
#define H_ 16
#define I_ 512
#define E_ 512

// Algebraic collapse (verified rounds 1-2, absmax <= 0.25):
//   softmax(axis=2) followed by sum(axis=2) makes attention exact identity on V:
//   emb[b,h,e] = sum_i x[b,i,e] * W_v[h,i,e];  out = emb @ mlp_w^T + mlp_b.

#define NSLICE 16   // i-slices for emb partials (32 i's each)
#define KSPLIT 8    // k-split for mlp partials (64 k's each)

#define MLP_STEP(ACC, AV)                                                  \
    ACC.x = fmaf(AV.x, w0.x, fmaf(AV.y, w1.x, fmaf(AV.z, w2.x, fmaf(AV.w, w3.x, ACC.x)))); \
    ACC.y = fmaf(AV.x, w0.y, fmaf(AV.y, w1.y, fmaf(AV.z, w2.y, fmaf(AV.w, w3.y, ACC.y)))); \
    ACC.z = fmaf(AV.x, w0.z, fmaf(AV.y, w1.z, fmaf(AV.z, w2.z, fmaf(AV.w, w3.z, ACC.z)))); \
    ACC.w = fmaf(AV.x, w0.w, fmaf(AV.y, w1.w, fmaf(AV.z, w2.w, fmaf(AV.w, w3.w, ACC.w))));

// ---------------------------------------------------------------------------
// Fused cooperative kernel: all 4 phases, 3 grid syncs.
// 512 blocks x 256 threads, 64 KB LDS aliased per phase -> 2 blocks/CU
// (co-residency: 512 blocks = 2 x 256 CUs; __launch_bounds__(256,2) keeps
// VGPR <= 256 so occupancy is LDS-limited at exactly 2 blocks/CU).
// ---------------------------------------------------------------------------
__global__ __launch_bounds__(256, 2) void k_fused(
    const float* __restrict__ x, const float* __restrict__ Wv,
    const float* __restrict__ W, const float* __restrict__ bias,
    float* __restrict__ epart, float* __restrict__ emb,
    float* __restrict__ mpart, float* __restrict__ out) {
    __shared__ __align__(16) float lds[16384];  // 64 KB, aliased per phase
    const int bid = blockIdx.x;
    const int t   = (int)threadIdx.x;

    // ---- Phase 1: emb slice partials (identical math to k_emb_part) ----
    // bid -> (ex, b-half, h-half, slice); linearization matches the old
    // grid (8,2,32) so the 4 sibling blocks sharing x/Wv stay co-XCD.
    {
        const int ex    = bid & 7;
        const int by    = (bid >> 3) & 1;
        const int bz    = bid >> 4;            // 0..31
        const int e     = ex * 64 + (t & 63);
        const int b0    = by * 8;
        const int h0    = (bz & 1) * 8;
        const int slice = bz >> 1;             // 0..15
        const int lane  = t & 63;
        const int wave  = t >> 6;              // 0..3

        float acc[8][8];
#pragma unroll
        for (int bi = 0; bi < 8; ++bi)
#pragma unroll
            for (int hj = 0; hj < 8; ++hj) acc[bi][hj] = 0.0f;

        const int ibase = slice * 32 + wave * 8;
        const float* xp[8];
        const float* wp[8];
#pragma unroll
        for (int bi = 0; bi < 8; ++bi)
            xp[bi] = x + ((size_t)(b0 + bi) * I_ + ibase) * E_ + e;
#pragma unroll
        for (int hj = 0; hj < 8; ++hj)
            wp[hj] = Wv + ((size_t)(h0 + hj) * I_ + ibase) * E_ + e;

        for (int ii = 0; ii < 8; ++ii) {
            const int off = ii * E_;
            float xv[8], wv[8];
#pragma unroll
            for (int bi = 0; bi < 8; ++bi) xv[bi] = xp[bi][off];
#pragma unroll
            for (int hj = 0; hj < 8; ++hj) wv[hj] = wp[hj][off];
#pragma unroll
            for (int bi = 0; bi < 8; ++bi)
#pragma unroll
                for (int hj = 0; hj < 8; ++hj)
                    acc[bi][hj] = fmaf(xv[bi], wv[hj], acc[bi][hj]);
        }

        // cross-wave reduce through LDS (stride-1 in lane -> conflict-free)
        float (*red)[64][64] = (float (*)[64][64])lds;
#pragma unroll
        for (int bi = 0; bi < 8; ++bi)
#pragma unroll
            for (int hj = 0; hj < 8; ++hj)
                red[wave][bi * 8 + hj][lane] = acc[bi][hj];
        __syncthreads();

        for (int tt = t; tt < 64 * 64; tt += 256) {
            const int pair = tt >> 6, le = tt & 63;
            float s = (red[0][pair][le] + red[1][pair][le]) +
                      (red[2][pair][le] + red[3][pair][le]);
            const int row = (b0 + (pair >> 3)) * H_ + h0 + (pair & 7);
            epart[((size_t)slice * (B_ * H_) + row) * E_ + ex * 64 + le] = s;
        }
    }
    cg::this_grid().sync();

    // ---- Phase 2: emb = sum of NSLICE partials. Spread over ALL 512
    // blocks (1 wave each) so the 8.5 MB of reads use the whole chip. ----
    if (t < 64) {
        const int idx = bid * 64 + t;                  // < 32768 float4
        const int sl  = (B_ * H_ * E_) / 4;
        const float4* p = (const float4*)epart;
        float4 s = p[idx];
#pragma unroll
        for (int j = 1; j < NSLICE; ++j) {
            float4 v = p[(size_t)j * sl + idx];
            s.x += v.x; s.y += v.y; s.z += v.z; s.w += v.w;
        }
        ((float4*)emb)[idx] = s;
    }
    cg::this_grid().sync();

    // ---- Phase 3: K-split GEMM partials. out-tile 32r x 64c, k-chunk 64,
    // 256 threads (2r x 4c micro). A staged [r][k], W staged transposed
    // [k][c]: main-loop reads are broadcast / conflict-free b128. ----
    {
        const int cblk = bid & 7;          // 64-col tile
        const int rblk = (bid >> 3) & 7;   // 32-row tile
        const int kch  = bid >> 6;         // 0..7
        const int k0   = kch * 64;

        float (*As)[68] = (float (*)[68])lds;               //  32x68
        float (*Ws)[68] = (float (*)[68])(lds + 32 * 68);   //  64x68

        // stage A: 32r x 64k, 512 float4 -> 2/thread, coalesced along k
#pragma unroll
        for (int it = 0; it < 2; ++it) {
            const int f = t + it * 256;
            const int r = f >> 4, kq = f & 15;
            float4 v = *(const float4*)(emb + (size_t)(rblk * 32 + r) * E_ + k0 + kq * 4);
            *(float4*)&As[r][kq * 4] = v;
        }
        // stage W: 64c x 64k, 1024 float4 -> 4/thread, transposed scatter
#pragma unroll
        for (int it = 0; it < 4; ++it) {
            const int f = t + it * 256;
            const int c = f >> 4, kq = f & 15;
            float4 v = *(const float4*)(W + (size_t)(cblk * 64 + c) * E_ + k0 + kq * 4);
            Ws[kq * 4 + 0][c] = v.x;
            Ws[kq * 4 + 1][c] = v.y;
            Ws[kq * 4 + 2][c] = v.z;
            Ws[kq * 4 + 3][c] = v.w;
        }
        __syncthreads();

        const int tx = t & 15, ty = t >> 4;   // c-quad 0..15, r-pair 0..15
        const int c0 = tx * 4, r0 = ty * 2;

        float4 acc0 = {0, 0, 0, 0}, acc1 = {0, 0, 0, 0};
        for (int k = 0; k < 64; k += 4) {
            float4 a0 = *(const float4*)&As[r0 + 0][k];
            float4 a1 = *(const float4*)&As[r0 + 1][k];
            float4 w0 = *(const float4*)&Ws[k + 0][c0];
            float4 w1 = *(const float4*)&Ws[k + 1][c0];
            float4 w2 = *(const float4*)&Ws[k + 2][c0];
            float4 w3 = *(const float4*)&Ws[k + 3][c0];
            MLP_STEP(acc0, a0)
            MLP_STEP(acc1, a1)
        }

        float* dst = mpart + ((size_t)kch * (B_ * H_) + rblk * 32 + r0) * E_ +
                     cblk * 64 + c0;
        *(float4*)(dst + 0 * E_) = acc0;
        *(float4*)(dst + 1 * E_) = acc1;
    }
    cg::this_grid().sync();

    // ---- Phase 4: out = sum of KSPLIT partials + bias (all 512 blocks) ----
    if (t < 64) {
        const int idx = bid * 64 + t;                  // < 32768 float4
        const int sl  = (B_ * H_ * E_) / 4;
        const float4* p = (const float4*)mpart;
        float4 s = p[idx];
#pragma unroll
        for (int j = 1; j < KSPLIT; ++j) {
            float4 v = p[(size_t)j * sl + idx];
            s.x += v.x; s.y += v.y; s.z += v.z; s.w += v.w;
        }
        float4 bv = ((const float4*)bias)[idx & (E_ / 4 - 1)];
        s.x += bv.x; s.y += bv.y; s.z += bv.z; s.w += bv.w;
        ((float4*)out)[idx] = s;
    }
}

// ---------------------------------------------------------------------------
// Fallback path: the verified 4-kernel pipeline (used only if the
// cooperative launch is rejected, e.g. by graph capture).
// ---------------------------------------------------------------------------
__global__ __launch_bounds__(256) void k_emb_part(const float* __restrict__ x,
                                                  const float* __restrict__ Wv,
                                                  float* __restrict__ part) {
    const int e     = blockIdx.x * 64 + (threadIdx.x & 63);
    const int b0    = blockIdx.y * 8;
    const int h0    = (blockIdx.z & 1) * 8;
    const int slice = blockIdx.z >> 1;
    const int lane  = threadIdx.x & 63;
    const int wave  = threadIdx.x >> 6;

    float acc[8][8];
#pragma unroll
    for (int bi = 0; bi < 8; ++bi)
#pragma unroll
        for (int hj = 0; hj < 8; ++hj) acc[bi][hj] = 0.0f;

    const int ibase = slice * 32 + wave * 8;
    const float* xp[8];
    const float* wp[8];
#pragma unroll
    for (int bi = 0; bi < 8; ++bi)
        xp[bi] = x + ((size_t)(b0 + bi) * I_ + ibase) * E_ + e;
#pragma unroll
    for (int hj = 0; hj < 8; ++hj)
        wp[hj] = Wv + ((size_t)(h0 + hj) * I_ + ibase) * E_ + e;

    for (int ii = 0; ii < 8; ++ii) {
        const int off = ii * E_;
        float xv[8], wv[8];
#pragma unroll
        for (int bi = 0; bi < 8; ++bi) xv[bi] = xp[bi][off];
#pragma unroll
        for (int hj = 0; hj < 8; ++hj) wv[hj] = wp[hj][off];
#pragma unroll
        for (int bi = 0; bi < 8; ++bi)
#pragma unroll
            for (int hj = 0; hj < 8; ++hj)
                acc[bi][hj] = fmaf(xv[bi], wv[hj], acc[bi][hj]);
    }

    __shared__ float red[4][64][64];
#pragma unroll
    for (int bi = 0; bi < 8; ++bi)
#pragma unroll
        for (int hj = 0; hj < 8; ++hj)
            red[wave][bi * 8 + hj][lane] = acc[bi][hj];
    __syncthreads();

    for (int t = threadIdx.x; t < 64 * 64; t += 256) {
        const int pair = t >> 6, le = t & 63;
        float s = (red[0][pair][le] + red[1][pair][le]) +
                  (red[2][pair][le] + red[3][pair][le]);
        const int row = (b0 + (pair >> 3)) * H_ + h0 + (pair & 7);
        part[((size_t)slice * (B_ * H_) + row) * E_ + blockIdx.x * 64 + le] = s;
    }
}

__global__ __launch_bounds__(256) void k_emb_reduce(const float4* __restrict__ part,
                                                    float4* __restrict__ emb) {
    const int idx = blockIdx.x * 256 + threadIdx.x;
    const int sl  = (B_ * H_ * E_) / 4;
    float4 s = part[idx];
#pragma unroll
    for (int j = 1; j < NSLICE; ++j) {
        float4 p = part[(size_t)j * sl + idx];
        s.x += p.x; s.y += p.y; s.z += p.z; s.w += p.w;
    }
    emb[idx] = s;
}

__global__ __launch_bounds__(128) void k_mlp_part(const float* __restrict__ emb,
                                                  const float* __restrict__ W,
                                                  float* __restrict__ part) {
    const int cblk = blockIdx.x;
    const int rblk = blockIdx.y;
    const int k0   = blockIdx.z * 64;

    __shared__ float As[32][68];
    __shared__ float Ws[64][68];

    const int t = threadIdx.x;
    {
        const int r8 = t >> 4, kq = t & 15;
#pragma unroll
        for (int it = 0; it < 4; ++it) {
            const int r = r8 + it * 8;
            float4 v = *(const float4*)(emb + (size_t)(rblk * 32 + r) * E_ + k0 + kq * 4);
            *(float4*)&As[r][kq * 4] = v;
        }
    }
    {
        const int c8 = t >> 4, kq = t & 15;
#pragma unroll
        for (int it = 0; it < 8; ++it) {
            const int c = c8 + it * 8;
            float4 v = *(const float4*)(W + (size_t)(cblk * 64 + c) * E_ + k0 + kq * 4);
            Ws[kq * 4 + 0][c] = v.x;
            Ws[kq * 4 + 1][c] = v.y;
            Ws[kq * 4 + 2][c] = v.z;
            Ws[kq * 4 + 3][c] = v.w;
        }
    }
    __syncthreads();

    const int tx = t & 15, ty = t >> 4;
    const int c0 = tx * 4, r0 = ty * 4;

    float4 acc0 = {0, 0, 0, 0}, acc1 = {0, 0, 0, 0};
    float4 acc2 = {0, 0, 0, 0}, acc3 = {0, 0, 0, 0};

    for (int k = 0; k < 64; k += 4) {
        float4 a0 = *(const float4*)&As[r0 + 0][k];
        float4 a1 = *(const float4*)&As[r0 + 1][k];
        float4 a2 = *(const float4*)&As[r0 + 2][k];
        float4 a3 = *(const float4*)&As[r0 + 3][k];
        float4 w0 = *(const float4*)&Ws[k + 0][c0];
        float4 w1 = *(const float4*)&Ws[k + 1][c0];
        float4 w2 = *(const float4*)&Ws[k + 2][c0];
        float4 w3 = *(const float4*)&Ws[k + 3][c0];
        MLP_STEP(acc0, a0)
        MLP_STEP(acc1, a1)
        MLP_STEP(acc2, a2)
        MLP_STEP(acc3, a3)
    }

    float* dst = part + ((size_t)blockIdx.z * (B_ * H_) + rblk * 32 + r0) * E_ +
                 cblk * 64 + c0;
    *(float4*)(dst + 0 * E_) = acc0;
    *(float4*)(dst + 1 * E_) = acc1;
    *(float4*)(dst + 2 * E_) = acc2;
    *(float4*)(dst + 3 * E_) = acc3;
}

__global__ __launch_bounds__(256) void k_out(const float4* __restrict__ part,
                                             const float4* __restrict__ bias,
                                             float4* __restrict__ out) {
    const int idx = blockIdx.x * 256 + threadIdx.x;
    const int sl  = (B_ * H_ * E_) / 4;
    float4 s = part[idx];
#pragma unroll
    for (int j = 1; j < KSPLIT; ++j) {
        float4 p = part[(size_t)j * sl + idx];
        s.x += p.x; s.y += p.y; s.z += p.z; s.w += p.w;
    }
    float4 bv = bias[idx & (E_ / 4 - 1)];
    s.x += bv.x; s.y += bv.y; s.z += bv.z; s.w += bv.w;
    out[idx] = s;
}

extern "C" void kernel_launch(void* const* d_in, const int* in_sizes, int n_in,
                              void* d_out, int out_size, void* d_ws, size_t ws_size,
                              hipStream_t stream) {
    // setup_inputs order: x, W_q, W_k, W_v, mlp_w, mlp_b  (all fp32)
    const float* x     = (const float*)d_in[0];
    const float* W_v   = (const float*)d_in[3];
    const float* mlp_w = (const float*)d_in[4];
    const float* mlp_b = (const float*)d_in[5];
    float* out = (float*)d_out;

    // ws layout: emb partials (16 x 256 x 512 = 8 MB) | emb (512 KB) |
    //            mlp partials (8 x 256 x 512 = 4 MB)
    float* epart = (float*)d_ws;
    float* emb   = epart + (size_t)NSLICE * B_ * H_ * E_;
    float* mpart = emb + (size_t)B_ * H_ * E_;

    void* args[] = {(void*)&x,     (void*)&W_v, (void*)&mlp_w, (void*)&mlp_b,
                    (void*)&epart, (void*)&emb, (void*)&mpart, (void*)&out};
    hipError_t err = hipLaunchCooperativeKernel((const void*)k_fused, dim3(512),
                                                dim3(256), args, 0, stream);
    if (err != hipSuccess) {
        (void)hipGetLastError();  // clear; fall back to the 4-kernel pipeline
        dim3 g1(E_ / 64, B_ / 8, (H_ / 8) * NSLICE);
        k_emb_part<<<g1, 256, 0, stream>>>(x, W_v, epart);
        k_emb_reduce<<<(B_ * H_ * E_ / 4) / 256, 256, 0, stream>>>(
            (const float4*)epart, (float4*)emb);
        dim3 g3(E_ / 64, (B_ * H_) / 32, KSPLIT);
        k_mlp_part<<<g3, 128, 0, stream>>>(emb, mlp_w, mpart);
        k_out<<<(B_ * H_ * E_ / 4) / 256, 256, 0, stream>>>(
            (const float4*)mpart, (const float4*)mlp_b, (float4*)out);
    }
}

// Round 2
// 148.418 us; speedup vs baseline: 1.9676x; 1.9676x over previous
//
#include <hip/hip_runtime.h>

// Problem constants (reference: B,H,I,E = 16,16,512,512)
#define B_ 16
#define H_ 16
#define I_ 512
#define E_ 512

// Algebraic collapse (verified earlier rounds, absmax <= 0.25):
//   softmax(axis=2) followed by sum(axis=2) makes attention exact identity on V:
//   emb[b,h,e] = sum_i x[b,i,e] * W_v[h,i,e];  out = emb @ mlp_w^T + mlp_b.
//
// Round-1 lesson: cooperative grid.sync costs ~50us each on 8-XCD gfx950
// (k_fused 186us, VALUBusy 2.3%) -> fused kernel reverted. This round: the
// verified 4-kernel pipeline with k_out folded into k_mlp_part via split-K
// last-block-done (device-scope atomics, no grid barrier). Counters are
// zeroed each iteration by k_emb_reduce (stream-ordered before k_mlp_part,
// so workspace re-poisoning between iterations cannot corrupt them).

#define NSLICE 16   // i-slices for emb partials (32 i's each)
#define KSPLIT 8    // k-split for mlp partials (64 k's each)

// ---------------------------------------------------------------------------
// Kernel 1: partial emb with 8x8 register blocking. (verified, unchanged)
// Block: 8 b's x 8 h's x 64 e's (lane=e), one slice of 32 i's split 8/wave.
// Grid (E/64=8, B/8=2, (H/8=2)*16 slices=32) = 512 blocks, 256 threads.
// ---------------------------------------------------------------------------
__global__ __launch_bounds__(256) void k_emb_part(const float* __restrict__ x,
                                                  const float* __restrict__ Wv,
                                                  float* __restrict__ part) {
    const int e     = blockIdx.x * 64 + (threadIdx.x & 63);
    const int b0    = blockIdx.y * 8;
    const int h0    = (blockIdx.z & 1) * 8;
    const int slice = blockIdx.z >> 1;        // 0..15
    const int lane  = threadIdx.x & 63;
    const int wave  = threadIdx.x >> 6;       // 0..3

    float acc[8][8];
#pragma unroll
    for (int bi = 0; bi < 8; ++bi)
#pragma unroll
        for (int hj = 0; hj < 8; ++hj) acc[bi][hj] = 0.0f;

    const int ibase = slice * 32 + wave * 8;
    const float* xp[8];
    const float* wp[8];
#pragma unroll
    for (int bi = 0; bi < 8; ++bi)
        xp[bi] = x + ((size_t)(b0 + bi) * I_ + ibase) * E_ + e;
#pragma unroll
    for (int hj = 0; hj < 8; ++hj)
        wp[hj] = Wv + ((size_t)(h0 + hj) * I_ + ibase) * E_ + e;

    for (int ii = 0; ii < 8; ++ii) {
        const int off = ii * E_;
        float xv[8], wv[8];
#pragma unroll
        for (int bi = 0; bi < 8; ++bi) xv[bi] = xp[bi][off];
#pragma unroll
        for (int hj = 0; hj < 8; ++hj) wv[hj] = wp[hj][off];
#pragma unroll
        for (int bi = 0; bi < 8; ++bi)
#pragma unroll
            for (int hj = 0; hj < 8; ++hj)
                acc[bi][hj] = fmaf(xv[bi], wv[hj], acc[bi][hj]);
    }

    // cross-wave reduce (4 i-subslices) through LDS; stride-1 in lane ->
    // conflict-free.
    __shared__ float red[4][64][64];  // 64 KB -> 2 blocks/CU
#pragma unroll
    for (int bi = 0; bi < 8; ++bi)
#pragma unroll
        for (int hj = 0; hj < 8; ++hj)
            red[wave][bi * 8 + hj][lane] = acc[bi][hj];
    __syncthreads();

    for (int t = threadIdx.x; t < 64 * 64; t += 256) {
        const int pair = t >> 6, le = t & 63;
        float s = (red[0][pair][le] + red[1][pair][le]) +
                  (red[2][pair][le] + red[3][pair][le]);
        const int row = (b0 + (pair >> 3)) * H_ + h0 + (pair & 7);
        part[((size_t)slice * (B_ * H_) + row) * E_ + blockIdx.x * 64 + le] = s;
    }
}

// ---------------------------------------------------------------------------
// Kernel 2: emb = sum of NSLICE partial slices (float4 lanes), PLUS zeroing
// of the 64 split-K tile counters used by kernel 3 (stream order guarantees
// the zeros land before any k_mlp_part atomic).
// ---------------------------------------------------------------------------
__global__ __launch_bounds__(256) void k_emb_reduce(const float4* __restrict__ part,
                                                    float4* __restrict__ emb,
                                                    int* __restrict__ counters) {
    if (blockIdx.x == 0 && threadIdx.x < 64) counters[threadIdx.x] = 0;

    const int idx = blockIdx.x * 256 + threadIdx.x;
    const int sl  = (B_ * H_ * E_) / 4;
    float4 s = part[idx];
#pragma unroll
    for (int j = 1; j < NSLICE; ++j) {
        float4 p = part[(size_t)j * sl + idx];
        s.x += p.x; s.y += p.y; s.z += p.z; s.w += p.w;
    }
    emb[idx] = s;
}

// ---------------------------------------------------------------------------
// Kernel 3: K-split GEMM partials + fused last-block-done reduction.
// out-tile 32r x 64c, k-chunk 64, 4x4 micro. Grid (8,8,KSPLIT=8) = 512
// blocks, 128 threads. Each block stores its partial, releases (fence),
// bumps the per-tile counter (ACQ_REL, agent scope); the 8th block re-reads
// the other 7 partials (own partial kept in registers), adds bias, writes out.
// No grid-wide sync anywhere.
// ---------------------------------------------------------------------------
__global__ __launch_bounds__(128) void k_mlp_part(const float* __restrict__ emb,
                                                  const float* __restrict__ W,
                                                  const float* __restrict__ bias,
                                                  float* __restrict__ part,
                                                  int* __restrict__ counters,
                                                  float* __restrict__ out) {
    const int cblk = blockIdx.x;   // 64-col tile
    const int rblk = blockIdx.y;   // 32-row tile
    const int kch  = blockIdx.z;   // 0..7
    const int k0   = kch * 64;

    __shared__ float As[32][68];   // [r][k]  8.7 KB
    __shared__ float Ws[64][68];   // [k][c] 17.4 KB

    const int t = threadIdx.x;

    // stage A: 32r x 64k, float4 along k (coalesced), direct b128 LDS store
    {
        const int r8 = t >> 4, kq = t & 15;
#pragma unroll
        for (int it = 0; it < 4; ++it) {
            const int r = r8 + it * 8;
            float4 v = *(const float4*)(emb + (size_t)(rblk * 32 + r) * E_ + k0 + kq * 4);
            *(float4*)&As[r][kq * 4] = v;
        }
    }
    // stage W: 64c x 64k, float4 along k (coalesced), transposed scalar stores
    {
        const int c8 = t >> 4, kq = t & 15;
#pragma unroll
        for (int it = 0; it < 8; ++it) {
            const int c = c8 + it * 8;
            float4 v = *(const float4*)(W + (size_t)(cblk * 64 + c) * E_ + k0 + kq * 4);
            Ws[kq * 4 + 0][c] = v.x;
            Ws[kq * 4 + 1][c] = v.y;
            Ws[kq * 4 + 2][c] = v.z;
            Ws[kq * 4 + 3][c] = v.w;
        }
    }
    __syncthreads();

    const int tx = t & 15, ty = t >> 4;   // c-quad 0..15, r-quad 0..7
    const int c0 = tx * 4, r0 = ty * 4;

    float4 acc0 = {0, 0, 0, 0}, acc1 = {0, 0, 0, 0};
    float4 acc2 = {0, 0, 0, 0}, acc3 = {0, 0, 0, 0};

    for (int k = 0; k < 64; k += 4) {
        float4 a0 = *(const float4*)&As[r0 + 0][k];
        float4 a1 = *(const float4*)&As[r0 + 1][k];
        float4 a2 = *(const float4*)&As[r0 + 2][k];
        float4 a3 = *(const float4*)&As[r0 + 3][k];
        float4 w0 = *(const float4*)&Ws[k + 0][c0];
        float4 w1 = *(const float4*)&Ws[k + 1][c0];
        float4 w2 = *(const float4*)&Ws[k + 2][c0];
        float4 w3 = *(const float4*)&Ws[k + 3][c0];
#define MLP_STEP(ACC, AV)                                                  \
        ACC.x = fmaf(AV.x, w0.x, fmaf(AV.y, w1.x, fmaf(AV.z, w2.x, fmaf(AV.w, w3.x, ACC.x)))); \
        ACC.y = fmaf(AV.x, w0.y, fmaf(AV.y, w1.y, fmaf(AV.z, w2.y, fmaf(AV.w, w3.y, ACC.y)))); \
        ACC.z = fmaf(AV.x, w0.z, fmaf(AV.y, w1.z, fmaf(AV.z, w2.z, fmaf(AV.w, w3.z, ACC.z)))); \
        ACC.w = fmaf(AV.x, w0.w, fmaf(AV.y, w1.w, fmaf(AV.z, w2.w, fmaf(AV.w, w3.w, ACC.w))));
        MLP_STEP(acc0, a0)
        MLP_STEP(acc1, a1)
        MLP_STEP(acc2, a2)
        MLP_STEP(acc3, a3)
#undef MLP_STEP
    }

    // store this k-chunk's partial tile
    const size_t sl = (size_t)(B_ * H_) * E_;
    float* dst = part + (size_t)kch * sl + (size_t)(rblk * 32 + r0) * E_ +
                 cblk * 64 + c0;
    *(float4*)(dst + 0 * E_) = acc0;
    *(float4*)(dst + 1 * E_) = acc1;
    *(float4*)(dst + 2 * E_) = acc2;
    *(float4*)(dst + 3 * E_) = acc3;

    // ---- last-block-done reduction (split-K epilogue) ----
    __threadfence();                      // release: partial visible device-wide
    __shared__ int is_last;
    if (t == 0) {
        int prev = __hip_atomic_fetch_add(&counters[rblk * 8 + cblk], 1,
                                          __ATOMIC_ACQ_REL,
                                          __HIP_MEMORY_SCOPE_AGENT);
        is_last = (prev == KSPLIT - 1);
    }
    __syncthreads();
    if (!is_last) return;
    __threadfence();                      // acquire: see peers' partials

    // winner: own partial already in acc0..acc3; add the other 7 + bias
#pragma unroll
    for (int j = 0; j < KSPLIT; ++j) {
        if (j == kch) continue;
        const float* p = part + (size_t)j * sl + (size_t)(rblk * 32 + r0) * E_ +
                         cblk * 64 + c0;
        float4 p0 = *(const float4*)(p + 0 * E_);
        float4 p1 = *(const float4*)(p + 1 * E_);
        float4 p2 = *(const float4*)(p + 2 * E_);
        float4 p3 = *(const float4*)(p + 3 * E_);
        acc0.x += p0.x; acc0.y += p0.y; acc0.z += p0.z; acc0.w += p0.w;
        acc1.x += p1.x; acc1.y += p1.y; acc1.z += p1.z; acc1.w += p1.w;
        acc2.x += p2.x; acc2.y += p2.y; acc2.z += p2.z; acc2.w += p2.w;
        acc3.x += p3.x; acc3.y += p3.y; acc3.z += p3.z; acc3.w += p3.w;
    }

    float4 bv = *(const float4*)(bias + cblk * 64 + c0);
    acc0.x += bv.x; acc0.y += bv.y; acc0.z += bv.z; acc0.w += bv.w;
    acc1.x += bv.x; acc1.y += bv.y; acc1.z += bv.z; acc1.w += bv.w;
    acc2.x += bv.x; acc2.y += bv.y; acc2.z += bv.z; acc2.w += bv.w;
    acc3.x += bv.x; acc3.y += bv.y; acc3.z += bv.z; acc3.w += bv.w;

    float* o = out + (size_t)(rblk * 32 + r0) * E_ + cblk * 64 + c0;
    *(float4*)(o + 0 * E_) = acc0;
    *(float4*)(o + 1 * E_) = acc1;
    *(float4*)(o + 2 * E_) = acc2;
    *(float4*)(o + 3 * E_) = acc3;
}

extern "C" void kernel_launch(void* const* d_in, const int* in_sizes, int n_in,
                              void* d_out, int out_size, void* d_ws, size_t ws_size,
                              hipStream_t stream) {
    // setup_inputs order: x, W_q, W_k, W_v, mlp_w, mlp_b  (all fp32)
    const float* x     = (const float*)d_in[0];
    const float* W_v   = (const float*)d_in[3];
    const float* mlp_w = (const float*)d_in[4];
    const float* mlp_b = (const float*)d_in[5];
    float* out = (float*)d_out;

    // ws layout: emb partials (16 x 256 x 512 = 8 MB) | emb (512 KB) |
    //            mlp partials (8 x 256 x 512 = 4 MB) | 64 tile counters
    float* epart   = (float*)d_ws;
    float* emb     = epart + (size_t)NSLICE * B_ * H_ * E_;
    float* mpart   = emb + (size_t)B_ * H_ * E_;
    int*   counters = (int*)(mpart + (size_t)KSPLIT * B_ * H_ * E_);

    dim3 g1(E_ / 64, B_ / 8, (H_ / 8) * NSLICE);   // (8,2,32) = 512 blocks
    k_emb_part<<<g1, 256, 0, stream>>>(x, W_v, epart);

    k_emb_reduce<<<(B_ * H_ * E_ / 4) / 256, 256, 0, stream>>>(
        (const float4*)epart, (float4*)emb, counters);

    dim3 g3(E_ / 64, (B_ * H_) / 32, KSPLIT);      // (8,8,8) = 512 blocks
    k_mlp_part<<<g3, 128, 0, stream>>>(emb, mlp_w, mlp_b, mpart, counters, out);
}

// Round 4
// 112.806 us; speedup vs baseline: 2.5887x; 1.3157x over previous
//
#include <hip/hip_runtime.h>

// Problem constants (reference: B,H,I,E = 16,16,512,512)
#define B_ 16
#define H_ 16
#define I_ 512
#define E_ 512

// Algebraic collapse (verified earlier rounds, absmax <= 0.25):
//   softmax(axis=2) followed by sum(axis=2) makes attention exact identity on V:
//   emb[b,h,e] = sum_i x[b,i,e] * W_v[h,i,e];  out = emb @ mlp_w^T + mlp_b.
//
// Round-1 lesson: cooperative grid.sync ~50us each on 8-XCD gfx950 -> dead.
// Round-2 lesson: __threadfence() (device-scope release/acquire) lowers to
// per-XCD L2 writeback/invalidate; 512 blocks doing it serialized k_mlp_part
// to 47us -> split-K atomic epilogues are dead too. Dependencies stay on
// kernel-launch boundaries (~2us each).
// Round-3: container infra failure (no data) -> identical resubmit of the
// Round-2 proposal: baseline 4-kernel pipeline; k_mlp_part rebuilt as
// 256-thread 64x64x64 tiles with XOR quad-swizzled LDS (both write and read
// sides), removing the 8-way Ws write conflicts and 4-way As read aliasing.

#define NSLICE 16   // i-slices for emb partials (32 i's each)
#define KSPLIT 8    // k-split for mlp partials (64 k's each)

// ---------------------------------------------------------------------------
// Kernel 1: partial emb with 8x8 register blocking. (verified, unchanged)
// Block: 8 b's x 8 h's x 64 e's (lane=e), one slice of 32 i's split 8/wave.
// Grid (E/64=8, B/8=2, (H/8=2)*16 slices=32) = 512 blocks, 256 threads.
// ---------------------------------------------------------------------------
__global__ __launch_bounds__(256) void k_emb_part(const float* __restrict__ x,
                                                  const float* __restrict__ Wv,
                                                  float* __restrict__ part) {
    const int e     = blockIdx.x * 64 + (threadIdx.x & 63);
    const int b0    = blockIdx.y * 8;
    const int h0    = (blockIdx.z & 1) * 8;
    const int slice = blockIdx.z >> 1;        // 0..15
    const int lane  = threadIdx.x & 63;
    const int wave  = threadIdx.x >> 6;       // 0..3

    float acc[8][8];
#pragma unroll
    for (int bi = 0; bi < 8; ++bi)
#pragma unroll
        for (int hj = 0; hj < 8; ++hj) acc[bi][hj] = 0.0f;

    const int ibase = slice * 32 + wave * 8;
    const float* xp[8];
    const float* wp[8];
#pragma unroll
    for (int bi = 0; bi < 8; ++bi)
        xp[bi] = x + ((size_t)(b0 + bi) * I_ + ibase) * E_ + e;
#pragma unroll
    for (int hj = 0; hj < 8; ++hj)
        wp[hj] = Wv + ((size_t)(h0 + hj) * I_ + ibase) * E_ + e;

    for (int ii = 0; ii < 8; ++ii) {
        const int off = ii * E_;
        float xv[8], wv[8];
#pragma unroll
        for (int bi = 0; bi < 8; ++bi) xv[bi] = xp[bi][off];
#pragma unroll
        for (int hj = 0; hj < 8; ++hj) wv[hj] = wp[hj][off];
#pragma unroll
        for (int bi = 0; bi < 8; ++bi)
#pragma unroll
            for (int hj = 0; hj < 8; ++hj)
                acc[bi][hj] = fmaf(xv[bi], wv[hj], acc[bi][hj]);
    }

    // cross-wave reduce (4 i-subslices) through LDS; stride-1 in lane ->
    // conflict-free.
    __shared__ float red[4][64][64];  // 64 KB -> 2 blocks/CU
#pragma unroll
    for (int bi = 0; bi < 8; ++bi)
#pragma unroll
        for (int hj = 0; hj < 8; ++hj)
            red[wave][bi * 8 + hj][lane] = acc[bi][hj];
    __syncthreads();

    for (int t = threadIdx.x; t < 64 * 64; t += 256) {
        const int pair = t >> 6, le = t & 63;
        float s = (red[0][pair][le] + red[1][pair][le]) +
                  (red[2][pair][le] + red[3][pair][le]);
        const int row = (b0 + (pair >> 3)) * H_ + h0 + (pair & 7);
        part[((size_t)slice * (B_ * H_) + row) * E_ + blockIdx.x * 64 + le] = s;
    }
}

// ---------------------------------------------------------------------------
// Kernel 2: emb = sum of NSLICE partial slices (float4 lanes). (unchanged)
// ---------------------------------------------------------------------------
__global__ __launch_bounds__(256) void k_emb_reduce(const float4* __restrict__ part,
                                                    float4* __restrict__ emb) {
    const int idx = blockIdx.x * 256 + threadIdx.x;
    const int sl  = (B_ * H_ * E_) / 4;
    float4 s = part[idx];
#pragma unroll
    for (int j = 1; j < NSLICE; ++j) {
        float4 p = part[(size_t)j * sl + idx];
        s.x += p.x; s.y += p.y; s.z += p.z; s.w += p.w;
    }
    emb[idx] = s;
}

// ---------------------------------------------------------------------------
// Kernel 3: K-split GEMM partials, REBUILT.
// out-tile 64r x 64c, k-chunk 64, 4x4 micro, 256 threads.
// Grid (E/64=8, 256rows/64=4, KSPLIT=8) = 256 blocks.
// LDS 34.8 KB: As[64][68] ([r][k]) + Ws[64][68] ([k][c] transposed).
// XOR quad-swizzle on BOTH tiles: phys_quad = logical_quad ^ (row>>2),
// applied identically on the write and read sides (reg-staged, so the
// both-sides rule for swizzles holds). Derivation: all LDS accesses land
// at <=2-way bank aliasing (free on CDNA4); removes the measured 458752
// conflict cycles of the old 8-way Ws scatter.
// Per wave-kquad: 8 ds_read_b128 (mostly broadcast) vs 128 fma-cycles ->
// compute-bound. Accumulation order per output identical to baseline.
// ---------------------------------------------------------------------------
__global__ __launch_bounds__(256) void k_mlp_part(const float* __restrict__ emb,
                                                  const float* __restrict__ W,
                                                  float* __restrict__ part) {
    const int cblk = blockIdx.x;   // 64-col tile, 0..7
    const int rblk = blockIdx.y;   // 64-row tile, 0..3
    const int kch  = blockIdx.z;   // 0..7
    const int k0   = kch * 64;

    __shared__ float As[64][68];   // [r][swizzled k]   17.4 KB
    __shared__ float Ws[64][68];   // [k][swizzled c]   17.4 KB

    const int t = threadIdx.x;

    // stage A: 64r x 64k, 1024 float4, 4/thread, coalesced along k.
    // LDS write at phys quad = kq ^ (r>>2): bank histogram perfectly even.
#pragma unroll
    for (int it = 0; it < 4; ++it) {
        const int f = t + it * 256;
        const int r = f >> 4, kq = f & 15;
        float4 v = *(const float4*)(emb + (size_t)(rblk * 64 + r) * E_ + k0 + kq * 4);
        *(float4*)&As[r][((kq ^ (r >> 2)) & 15) * 4] = v;
    }
    // stage W transposed: 64c x 64k, 1024 float4, 4/thread, coalesced along k.
    // Scalar scatter to rows kq*4+j at phys quad = (c>>2) ^ kq: rows kq and
    // kq+8 alias 2-way (free); old layout was 8-way.
#pragma unroll
    for (int it = 0; it < 4; ++it) {
        const int f = t + it * 256;
        const int c = f >> 4, kq = f & 15;
        float4 v = *(const float4*)(W + (size_t)(cblk * 64 + c) * E_ + k0 + kq * 4);
        const int pc = (((c >> 2) ^ kq) & 15) * 4 + (c & 3);
        Ws[kq * 4 + 0][pc] = v.x;
        Ws[kq * 4 + 1][pc] = v.y;
        Ws[kq * 4 + 2][pc] = v.z;
        Ws[kq * 4 + 3][pc] = v.w;
    }
    __syncthreads();

    const int tx = t & 15, ty = t >> 4;   // c-quad 0..15, r-quad 0..15
    const int c0 = tx * 4, r0 = ty * 4;

    float4 acc0 = {0, 0, 0, 0}, acc1 = {0, 0, 0, 0};
    float4 acc2 = {0, 0, 0, 0}, acc3 = {0, 0, 0, 0};

    for (int k = 0; k < 64; k += 4) {
        const int K  = k >> 2;
        const int ac = ((K ^ ty) & 15) * 4;   // As rows r0..r0+3 share r>>2 = ty
        const int wc = ((tx ^ K) & 15) * 4;   // Ws rows k..k+3 share row>>2 = K
        float4 a0 = *(const float4*)&As[r0 + 0][ac];
        float4 a1 = *(const float4*)&As[r0 + 1][ac];
        float4 a2 = *(const float4*)&As[r0 + 2][ac];
        float4 a3 = *(const float4*)&As[r0 + 3][ac];
        float4 w0 = *(const float4*)&Ws[k + 0][wc];
        float4 w1 = *(const float4*)&Ws[k + 1][wc];
        float4 w2 = *(const float4*)&Ws[k + 2][wc];
        float4 w3 = *(const float4*)&Ws[k + 3][wc];
#define MLP_STEP(ACC, AV)                                                  \
        ACC.x = fmaf(AV.x, w0.x, fmaf(AV.y, w1.x, fmaf(AV.z, w2.x, fmaf(AV.w, w3.x, ACC.x)))); \
        ACC.y = fmaf(AV.x, w0.y, fmaf(AV.y, w1.y, fmaf(AV.z, w2.y, fmaf(AV.w, w3.y, ACC.y)))); \
        ACC.z = fmaf(AV.x, w0.z, fmaf(AV.y, w1.z, fmaf(AV.z, w2.z, fmaf(AV.w, w3.z, ACC.z)))); \
        ACC.w = fmaf(AV.x, w0.w, fmaf(AV.y, w1.w, fmaf(AV.z, w2.w, fmaf(AV.w, w3.w, ACC.w))));
        MLP_STEP(acc0, a0)
        MLP_STEP(acc1, a1)
        MLP_STEP(acc2, a2)
        MLP_STEP(acc3, a3)
#undef MLP_STEP
    }

    float* dst = part + ((size_t)kch * (B_ * H_) + rblk * 64 + r0) * E_ +
                 cblk * 64 + c0;
    *(float4*)(dst + 0 * E_) = acc0;
    *(float4*)(dst + 1 * E_) = acc1;
    *(float4*)(dst + 2 * E_) = acc2;
    *(float4*)(dst + 3 * E_) = acc3;
}

// ---------------------------------------------------------------------------
// Kernel 4: out = sum of KSPLIT partials + bias. (unchanged)
// ---------------------------------------------------------------------------
__global__ __launch_bounds__(256) void k_out(const float4* __restrict__ part,
                                             const float4* __restrict__ bias,
                                             float4* __restrict__ out) {
    const int idx = blockIdx.x * 256 + threadIdx.x;   // < 32768
    const int sl  = (B_ * H_ * E_) / 4;
    float4 s = part[idx];
#pragma unroll
    for (int j = 1; j < KSPLIT; ++j) {
        float4 p = part[(size_t)j * sl + idx];
        s.x += p.x; s.y += p.y; s.z += p.z; s.w += p.w;
    }
    float4 bv = bias[idx & (E_ / 4 - 1)];
    s.x += bv.x; s.y += bv.y; s.z += bv.z; s.w += bv.w;
    out[idx] = s;
}

extern "C" void kernel_launch(void* const* d_in, const int* in_sizes, int n_in,
                              void* d_out, int out_size, void* d_ws, size_t ws_size,
                              hipStream_t stream) {
    // setup_inputs order: x, W_q, W_k, W_v, mlp_w, mlp_b  (all fp32)
    const float* x     = (const float*)d_in[0];
    const float* W_v   = (const float*)d_in[3];
    const float* mlp_w = (const float*)d_in[4];
    const float* mlp_b = (const float*)d_in[5];
    float* out = (float*)d_out;

    // ws layout: emb partials (16 x 256 x 512 = 8 MB) | emb (512 KB) |
    //            mlp partials (8 x 256 x 512 = 4 MB)
    float* epart = (float*)d_ws;
    float* emb   = epart + (size_t)NSLICE * B_ * H_ * E_;
    float* mpart = emb + (size_t)B_ * H_ * E_;

    dim3 g1(E_ / 64, B_ / 8, (H_ / 8) * NSLICE);   // (8,2,32) = 512 blocks
    k_emb_part<<<g1, 256, 0, stream>>>(x, W_v, epart);

    k_emb_reduce<<<(B_ * H_ * E_ / 4) / 256, 256, 0, stream>>>(
        (const float4*)epart, (float4*)emb);

    dim3 g3(E_ / 64, (B_ * H_) / 64, KSPLIT);      // (8,4,8) = 256 blocks
    k_mlp_part<<<g3, 256, 0, stream>>>(emb, mlp_w, mpart);

    k_out<<<(B_ * H_ * E_ / 4) / 256, 256, 0, stream>>>(
        (const float4*)mpart, (const float4*)mlp_b, (float4*)out);
}